// Round 1
// baseline (326.206 us; speedup 1.0000x reference)
//
#include <hip/hip_runtime.h>
#include <math.h>

// LiquidEchoHead: per-row interference -> alpha -> oscillator evolution.
//
// Restructured from block-per-row (4 waves + 2 barriers + LDS) to
// WAVE-per-row: each 64-lane wave owns one row end-to-end.
//  - no __syncthreads / LDS: row reduction is a __shfl_xor butterfly,
//    all lanes end up with the sum and compute alpha redundantly.
//  - phase 1 issues all 16 x-row float4 loads before any compute (MLP).
//  - x_real/x_imag held in registers across both phases (HBM-once).
//  - 2 independent accumulator pairs break the fma dependency chain.
// Identity: cos(a)cos(b)-sin(a)sin(b)=cos(a+b); cos(a)sin(b)+sin(a)cos(b)=sin(a+b)
// -> phase 2 needs one sincos on the summed angle.
// Supports D <= 2048 (8 float4 per lane), D % 4 == 0. Bench: B=8192, D=2048.

#define PHI_F 1.61803398874989f

__global__ __launch_bounds__(256, 4) void liquid_echo_kernel(
    const float* __restrict__ x_real, const float* __restrict__ x_imag,
    const float* __restrict__ t_arr,
    const float* __restrict__ w_query, const float* __restrict__ b_query,
    const float* __restrict__ w_osc,   const float* __restrict__ b_osc,
    const float* __restrict__ mem_r,   const float* __restrict__ mem_i,
    float* __restrict__ out_r, float* __restrict__ out_i,
    int D, int B, float inv_scale)
{
    const int wave = (int)threadIdx.x >> 6;
    const int lane = (int)threadIdx.x & 63;
    const int row  = ((int)blockIdx.x << 2) + wave;
    if (row >= B) return;

    const int d4 = D >> 2;                    // float4s per row (2048 -> 512)
    const size_t base4 = (size_t)row * d4;

    // Hide the (uniform) t load under everything else.
    const float tphi2 = 2.0f * PHI_F * t_arr[row];

    const float4* xr4 = (const float4*)x_real + base4;
    const float4* xi4 = (const float4*)x_imag + base4;
    const float4* wq4 = (const float4*)w_query;
    const float4* bq4 = (const float4*)b_query;

    // ---- Phase 1: interference reduction. Issue ALL x loads first. ----
    float4 xr[8], xi[8];
    #pragma unroll
    for (int c = 0; c < 8; ++c) {
        int idx = (c << 6) + lane;            // lanes consecutive -> coalesced
        if (idx < d4) {
            xr[c] = xr4[idx];
            xi[c] = xi4[idx];
        }
    }

    float accR0 = 0.f, accI0 = 0.f;           // 2 acc pairs: break fma chain
    float accR1 = 0.f, accI1 = 0.f;
    #pragma unroll
    for (int c = 0; c < 8; ++c) {
        int idx = (c << 6) + lane;
        if (idx < d4) {
            float4 wq = wq4[idx];             // L2-hot (shared across rows)
            float4 bq = bq4[idx];
            #pragma unroll
            for (int j = 0; j < 4; ++j) {
                float xrv = (&xr[c].x)[j];
                float xiv = (&xi[c].x)[j];
                float wl  = 1.f + fabsf((&wq.x)[j]);
                float theta = xrv * __builtin_amdgcn_rcpf(wl) + (&bq.x)[j];
                float sq, cq;
                __sincosf(theta, &sq, &cq);
                // interf_real += cq*xr + sq*xi ; interf_imag += cq*xi - sq*xr
                if (c & 1) {
                    accR1 = fmaf(cq, xrv, fmaf(sq, xiv, accR1));
                    accI1 = fmaf(cq, xiv, fmaf(-sq, xrv, accI1));
                } else {
                    accR0 = fmaf(cq, xrv, fmaf(sq, xiv, accR0));
                    accI0 = fmaf(cq, xiv, fmaf(-sq, xrv, accI0));
                }
            }
        }
    }
    float accR = accR0 + accR1;
    float accI = accI0 + accI1;

    // Butterfly reduction: every lane ends with the row totals. No LDS/barrier.
    #pragma unroll
    for (int off = 32; off > 0; off >>= 1) {
        accR += __shfl_xor(accR, off);
        accI += __shfl_xor(accI, off);
    }

    // All lanes compute alpha redundantly (cheap, uniform, no broadcast needed).
    float interf = sqrtf(fmaf(accR, accR, accI * accI));
    float z     = fmaf(interf, inv_scale, -2.0f);
    float sig   = 1.f / (1.f + __expf(-z));   // sigmoid(z)
    float alpha = __expf(sig - 1.f);          // exp(-k*(1-sig)), k=1
    float beta  = 1.f - alpha;

    // ---- Phase 2: oscillator evolution (x still in registers). ----
    const float4* wo4 = (const float4*)w_osc;
    const float4* bo4 = (const float4*)b_osc;
    const float4* mr4 = (const float4*)mem_r + base4;
    const float4* mi4 = (const float4*)mem_i + base4;
    float4* or4 = (float4*)out_r + base4;
    float4* oi4 = (float4*)out_i + base4;

    #pragma unroll
    for (int c = 0; c < 8; ++c) {
        int idx = (c << 6) + lane;
        if (idx < d4) {
            float4 wo = wo4[idx];
            float4 bo = bo4[idx];
            float4 mr = mr4[idx];
            float4 mi = mi4[idx];
            float4 oR, oI;
            #pragma unroll
            for (int j = 0; j < 4; ++j) {
                float br = fmaf(alpha, (&xr[c].x)[j], beta * (&mr.x)[j]);
                float bi = fmaf(alpha, (&xi[c].x)[j], beta * (&mi.x)[j]);
                float wl = 1.f + fabsf((&wo.x)[j]);
                float ang = fmaf(br + bi, __builtin_amdgcn_rcpf(wl),
                                 fmaf(2.f, (&bo.x)[j], tphi2));
                float sv, cv;
                __sincosf(ang, &sv, &cv);
                (&oR.x)[j] = cv;   // evolved_real = cos(theta_r + theta_i)
                (&oI.x)[j] = sv;   // evolved_imag = sin(theta_r + theta_i)
            }
            or4[idx] = oR;
            oi4[idx] = oI;
        }
    }
}

extern "C" void kernel_launch(void* const* d_in, const int* in_sizes, int n_in,
                              void* d_out, int out_size, void* d_ws, size_t ws_size,
                              hipStream_t stream) {
    const float* x_real   = (const float*)d_in[0];
    const float* x_imag   = (const float*)d_in[1];
    const float* t_arr    = (const float*)d_in[2];
    const float* w_query  = (const float*)d_in[3];
    const float* b_query  = (const float*)d_in[4];
    const float* w_osc    = (const float*)d_in[5];
    const float* b_osc    = (const float*)d_in[6];
    const float* mem_r    = (const float*)d_in[7];
    const float* mem_i    = (const float*)d_in[8];

    const int B = in_sizes[2];   // t is [B]
    const int D = in_sizes[3];   // w_query is [D]

    float* out_r = (float*)d_out;
    float* out_i = out_r + (size_t)B * D;

    const float inv_scale = 1.0f / sqrtf((float)D);

    const int grid = (B + 3) >> 2;           // 4 rows (waves) per block
    liquid_echo_kernel<<<grid, 256, 0, stream>>>(
        x_real, x_imag, t_arr, w_query, b_query, w_osc, b_osc,
        mem_r, mem_i, out_r, out_i, D, B, inv_scale);
}